// Round 3
// baseline (347.231 us; speedup 1.0000x reference)
//
#include <hip/hip_runtime.h>
#include <math.h>

#define HW 64
#define PPB 16   // 256-thread blocks per 64x64 image (wave = one row)
#define CSTR 8   // row-counter stride (words) to spread atomics across L2 channels

// f32 fast-raster record: 16 floats = 64 B
// float4 view: q0=(wx0,wy0,wc0,wx1) q1=(wy1,wc1,wx2,wy2) q2=(wc2,z0,z1,z2) q3=(epsf,epsz,pad,pad)
struct FaceRasF {
  float wx0, wy0, wc0;
  float wx1, wy1, wc1;
  float wx2, wy2, wc2;
  float z0, z1, z2;
  float epsf, epsz;
  float pad0, pad1;
};

__global__ void k_transform(const float* __restrict__ vert,
                            const float* __restrict__ rot,
                            const float* __restrict__ trans,
                            float* __restrict__ vs_cam,
                            float* __restrict__ vnorm, int B, int V) {
  int i = blockIdx.x * blockDim.x + threadIdx.x;
  if (i >= B * V) return;
  int b = i / V;
  float x = vert[i * 3 + 0], y = vert[i * 3 + 1], z = vert[i * 3 + 2];
  const float* R = rot + b * 9;
  const float* t = trans + b * 3;
  vs_cam[i * 3 + 0] = ((x * R[0] + y * R[1]) + z * R[2]) + t[0];
  vs_cam[i * 3 + 1] = ((x * R[3] + y * R[4]) + z * R[5]) + t[1];
  vs_cam[i * 3 + 2] = ((x * R[6] + y * R[7]) + z * R[8]) + t[2];
  vnorm[i * 3 + 0] = 0.f;   // zero-init here: saves a 192KB memset launch
  vnorm[i * 3 + 1] = 0.f;
  vnorm[i * 3 + 2] = 0.f;
}

// grid: ((F+255)/256, B) so each wave has uniform b (needed for ballot aggregation)
__global__ void k_facepre(const float* __restrict__ vs_cam,
                          const int* __restrict__ faces,
                          FaceRasF* __restrict__ frasF,
                          unsigned* __restrict__ yrange,
                          float* __restrict__ vnorm,
                          unsigned* __restrict__ rowcnt,
                          int B, int V, int F) {
  int f = blockIdx.x * blockDim.x + threadIdx.x;
  int b = blockIdx.y;
  bool valid = (f < F);
  int r0 = 1, r1 = 0;
  if (valid) {
    int i = b * F + f;
    int i0 = faces[f * 3 + 0], i1 = faces[f * 3 + 1], i2 = faces[f * 3 + 2];
    const float* c0 = vs_cam + (size_t)(b * V + i0) * 3;
    const float* c1 = vs_cam + (size_t)(b * V + i1) * 3;
    const float* c2 = vs_cam + (size_t)(b * V + i2) * 3;
    float c0x = c0[0], c0y = c0[1], c0z = c0[2];
    float c1x = c1[0], c1y = c1[1], c1z = c1[2];
    float c2x = c2[0], c2y = c2[1], c2z = c2[2];
    float v0x = c0x / c0z, v0y = c0y / c0z;
    float v1x = c1x / c1z, v1y = c1y / c1z;
    float v2x = c2x / c2z, v2y = c2y / c2z;
    float dx0 = v2x - v1x, dy0 = v2y - v1y;   // edge(v1,v2), anchor v1
    float dx1 = v0x - v2x, dy1 = v0y - v2y;   // edge(v2,v0), anchor v2
    float dx2 = v1x - v0x, dy2 = v1y - v0y;   // edge(v0,v1), anchor v0
    float Araw = dx2 * (v2y - v0y) - dy2 * (v2x - v0x);
    float A = (fabsf(Araw) < 1e-8f) ? 1e-8f : Araw;
    double invA = 1.0 / (double)A;
    double wx0 = -(double)dy0 * invA, wy0 = (double)dx0 * invA;
    double wc0 = ((double)dy0 * (double)v1x - (double)dx0 * (double)v1y) * invA;
    double wx1 = -(double)dy1 * invA, wy1 = (double)dx1 * invA;
    double wc1 = ((double)dy1 * (double)v2x - (double)dx1 * (double)v2y) * invA;
    double wx2 = -(double)dy2 * invA, wy2 = (double)dx2 * invA;
    double wc2 = ((double)dy2 * (double)v0x - (double)dx2 * (double)v0y) * invA;
    double m0 = fabs(wx0) + fabs(wy0) + fabs(wc0);
    double m1 = fabs(wx1) + fabs(wy1) + fabs(wc1);
    double m2 = fabs(wx2) + fabs(wy2) + fabs(wc2);
    double mm = fmax(fmax(m0, m1), m2);
    float epsf = fmaxf((float)(6e-7 * mm), 3e-7f);
    float zs = fabsf(c0z) + fabsf(c1z) + fabsf(c2z);
    float epsz = (epsf + 4e-6f) * zs;
    FaceRasF fr;
    fr.wx0 = (float)wx0; fr.wy0 = (float)wy0; fr.wc0 = (float)wc0;
    fr.wx1 = (float)wx1; fr.wy1 = (float)wy1; fr.wc1 = (float)wc1;
    fr.wx2 = (float)wx2; fr.wy2 = (float)wy2; fr.wc2 = (float)wc2;
    fr.z0 = c0z; fr.z1 = c1z; fr.z2 = c2z;
    fr.epsf = epsf; fr.epsz = epsz; fr.pad0 = 0.f; fr.pad1 = 0.f;
    frasF[i] = fr;
    // EXACT y-range of {dmin >= -band} via the barycentric slab:
    // w0+w1+w2 == 1, so dmin>=-b <=> all w_i>=-b, and y = sum w_i*v_iy over that
    // slab has exact extremes vext + b*(3*vext - sum).
    float band = fmaxf(0.202f, 1.6f * epsf);
    if (fabsf(Araw) < 1e-8f) {
      r0 = 0; r1 = 63;            // degenerate clamp: sum(w) != 1, no bound
    } else {
      float vmin = fminf(v0y, fminf(v1y, v2y));
      float vmax = fmaxf(v0y, fmaxf(v1y, v2y));
      float s3 = v0y + v1y + v2y;
      float b1 = band * 1.05f + 1e-4f;        // slack for f32 rounding
      float ylo = vmin + b1 * (3.f * vmin - s3);
      float yhi = vmax + b1 * (3.f * vmax - s3);
      if (yhi < -1.001f || ylo > 1.001f) { r0 = 1; r1 = 0; }
      else {
        r0 = max(0, (int)floorf((ylo + 1.0f) * 31.5f) - 1);
        r1 = min(63, (int)ceilf((yhi + 1.0f) * 31.5f) + 1);
        if (r0 > r1) { r0 = 1; r1 = 0; }
      }
    }
    yrange[i] = (unsigned)r0 | ((unsigned)r1 << 8);
    // face normal -> vertex normal scatter (f32 atomics)
    float e1x = c1x - c0x, e1y = c1y - c0y, e1z = c1z - c0z;
    float e2x = c2x - c0x, e2y = c2y - c0y, e2z = c2z - c0z;
    float nx = e1y * e2z - e1z * e2y;
    float ny = e1z * e2x - e1x * e2z;
    float nz = e1x * e2y - e1y * e2x;
    float* vn0 = vnorm + (size_t)(b * V + i0) * 3;
    float* vn1 = vnorm + (size_t)(b * V + i1) * 3;
    float* vn2 = vnorm + (size_t)(b * V + i2) * 3;
    atomicAdd(vn0 + 0, nx); atomicAdd(vn0 + 1, ny); atomicAdd(vn0 + 2, nz);
    atomicAdd(vn1 + 0, nx); atomicAdd(vn1 + 1, ny); atomicAdd(vn1 + 2, nz);
    atomicAdd(vn2 + 0, nx); atomicAdd(vn2 + 1, ny); atomicAdd(vn2 + 2, nz);
  }
  // wave-aggregated per-row face counting, trimmed to the wave's row union
  int lane = threadIdx.x & 63;
  bool has = valid && r0 <= r1;
  int rmin = has ? r0 : 64, rmax = has ? r1 : -1;
  for (int off = 32; off; off >>= 1) {
    rmin = min(rmin, __shfl_xor(rmin, off));
    rmax = max(rmax, __shfl_xor(rmax, off));
  }
  for (int r = rmin; r <= rmax; ++r) {
    unsigned long long m = __ballot(has && r >= r0 && r <= r1);
    if (m == 0ull) continue;
    if (lane == __ffsll(m) - 1)
      atomicAdd(&rowcnt[((b << 6) | r) * CSTR], (unsigned)__popcll(m));
  }
}

// exclusive scan of the 256 per-row counts (single block, Hillis-Steele in LDS)
__global__ void k_scan(const unsigned* __restrict__ rowcnt,
                       unsigned* __restrict__ rowstart) {
  __shared__ unsigned s[256];
  int t = threadIdx.x;
  s[t] = rowcnt[t * CSTR];
  __syncthreads();
  for (int off = 1; off < 256; off <<= 1) {
    unsigned v = (t >= off) ? s[t - off] : 0u;
    __syncthreads();
    s[t] += v;
    __syncthreads();
  }
  rowstart[t + 1] = s[t];
  if (t == 0) rowstart[0] = 0u;
}

// append faces into dense per-(b,row) CSR lists (wave-aggregated atomics)
__global__ void k_emit(const unsigned* __restrict__ yrange,
                       const unsigned* __restrict__ rowstart,
                       unsigned* __restrict__ rowfill,
                       unsigned* __restrict__ list,
                       unsigned lcap, int F) {
  int f = blockIdx.x * blockDim.x + threadIdx.x;
  int b = blockIdx.y;
  bool valid = (f < F);
  int r0 = 1, r1 = 0;
  if (valid) {
    unsigned r = yrange[(size_t)b * F + f];
    r0 = (int)(r & 0xffu); r1 = (int)(r >> 8);
  }
  int lane = threadIdx.x & 63;
  bool has = valid && r0 <= r1;
  int rmin = has ? r0 : 64, rmax = has ? r1 : -1;
  for (int off = 32; off; off >>= 1) {
    rmin = min(rmin, __shfl_xor(rmin, off));
    rmax = max(rmax, __shfl_xor(rmax, off));
  }
  for (int r = rmin; r <= rmax; ++r) {
    bool in = has && r >= r0 && r <= r1;
    unsigned long long m = __ballot(in);
    if (m == 0ull) continue;
    int row = (b << 6) | r;
    int leader = __ffsll(m) - 1;
    unsigned base = 0;
    if (lane == leader) base = atomicAdd(&rowfill[row * CSTR], (unsigned)__popcll(m));
    base = (unsigned)__shfl((int)base, leader);
    if (in) {
      unsigned pos = rowstart[row] + base +
                     (unsigned)__popcll(m & ((1ull << lane) - 1ull));
      if (pos < lcap) list[pos] = (unsigned)f;
    }
  }
}

// f32 screened raster: lane-parallel batch load + register-shuffle broadcast.
// (Old serial scalar-load walk was a ~1500cy/entry latency chain — Round-2 PMC.)
__global__ __launch_bounds__(256) void k_raster(
    const FaceRasF* __restrict__ frasF,
    const unsigned* __restrict__ yrange,
    const unsigned* __restrict__ rowstart,
    const unsigned* __restrict__ list,
    float* __restrict__ pz, unsigned* __restrict__ pbv,
    float* __restrict__ pl, float* __restrict__ pe,
    unsigned lcap, int F, int NC, int P) {
  int b = blockIdx.x / PPB;
  int pix = (blockIdx.x % PPB) * 256 + threadIdx.x;
  int chunk = blockIdx.y;
  int y = pix >> 6, x = pix & 63;
  const double step = 2.0 / 63.0;
  double pxd = (x == HW - 1) ? 1.0 : (x * step - 1.0);
  double pyd = (y == HW - 1) ? 1.0 : (y * step - 1.0);
  float pxf = (float)pxd, pyf = (float)pyd;
  const FaceRasF* __restrict__ fb = frasF + (size_t)b * F;
  float zminf = INFINITY;
  float weps = 0.f;
  int best = 0;
  bool flag = false;
  float lsum = 0.f;
  int lane = threadIdx.x & 63;

  int row = (b << 6) | y;                      // wave-uniform: wave = one row
  unsigned s = (unsigned)__builtin_amdgcn_readfirstlane((int)rowstart[row]);
  unsigned e = (unsigned)__builtin_amdgcn_readfirstlane((int)rowstart[row + 1]);
  if (e <= lcap) {
    // dense list path: entries for this row are complete in [s, e)
    unsigned len = e - s;
    unsigned per = (len + (unsigned)NC - 1) / (unsigned)NC;
    unsigned i0 = s + (unsigned)chunk * per;
    unsigned i1 = min(e, i0 + per);
    if (i0 < i1) {
      const float4* __restrict__ fb4 = (const float4*)fb;
      // lane j holds record of list[base+j]; py is wave-uniform so holder
      // pre-folds ce = fmaf(wy,py,wc); inner loop broadcasts 7 floats/face
      // (+5 gated), all loads coalesced/parallel instead of serial scalar.
      int cf; float4 cq0, cq1, cq2, cq3; float cc0, cc1, cc2;
      auto LOADB = [&](unsigned base, int& f_, float4& a0, float4& a1,
                       float4& a2, float4& a3, float& e0, float& e1, float& e2) {
        unsigned j = base + (unsigned)lane;
        if (j >= i1) j = i1 - 1;
        f_ = (int)list[j];
        size_t o = (size_t)f_ * 4;
        a0 = fb4[o + 0]; a1 = fb4[o + 1]; a2 = fb4[o + 2]; a3 = fb4[o + 3];
        e0 = fmaf(a0.y, pyf, a0.z);   // wy0*py + wc0
        e1 = fmaf(a1.x, pyf, a1.y);   // wy1*py + wc1
        e2 = fmaf(a1.w, pyf, a2.x);   // wy2*py + wc2
      };
      LOADB(i0, cf, cq0, cq1, cq2, cq3, cc0, cc1, cc2);
      unsigned cb = i0;
      while (cb < i1) {
        unsigned nb2 = cb + 64;
        int nf = cf; float4 nq0 = cq0, nq1 = cq1, nq2 = cq2, nq3 = cq3;
        float nc0 = cc0, nc1 = cc1, nc2 = cc2;
        if (nb2 < i1)                 // prefetch next batch during this one
          LOADB(nb2, nf, nq0, nq1, nq2, nq3, nc0, nc1, nc2);
        int n = (int)min(64u, i1 - cb);
        for (int k = 0; k < n; ++k) {
          float wx0 = __shfl(cq0.x, k), wx1 = __shfl(cq0.w, k), wx2 = __shfl(cq1.z, k);
          float c0 = __shfl(cc0, k), c1 = __shfl(cc1, k), c2 = __shfl(cc2, k);
          float ef = __shfl(cq3.x, k);
          float w0 = fmaf(wx0, pxf, c0);     // == fmaf(wx,px,fmaf(wy,py,wc)): bit-identical
          float w1 = fmaf(wx1, pxf, c1);
          float w2 = fmaf(wx2, pxf, c2);
          float dmin = fminf(fminf(w0, w1), w2);
          if (dmin > -0.2f) {
            // clip(dmin/sigma,-30,0): dmin<=-0.2 contributes <=2e-9, skipped
            float t = fminf(fmaxf(dmin * 100.0f, -30.0f), 0.0f);
            float pr = __expf(t);            // inside -> t=0 -> pr=1 exactly
            lsum += __logf(fmaf(-pr, 0.99999990f, 1.0f));
          }
          if (__any(dmin > -ef)) {           // wave-uniform gate: shuffles legal
            float z0 = __shfl(cq2.y, k), z1 = __shfl(cq2.z, k), z2 = __shfl(cq2.w, k);
            float ez = __shfl(cq3.y, k);
            int   fk = __shfl(cf, k);
            if (dmin > -ef) {
              float z = fmaf(w2, z2, fmaf(w1, z1, w0 * z0));
              bool contend = (z < zminf + ez + weps) & (z > -ez);
              flag |= (fabsf(dmin) < ef) & contend;            // inside-sign ambiguous
              flag |= (dmin >= 0.0f) & (fabsf(z) < ez);        // z>0 boundary ambiguous
              flag |= (dmin >= 0.0f) & (z > 0.0f) &
                      (fabsf(z - zminf) < ez + weps);          // z-order ambiguous
              if ((dmin >= 0.0f) & (z > 0.0f) & (z < zminf)) { // ties repaired in f64
                zminf = z; best = fk; weps = ez;
              }
            }
          }
        }
        cb = nb2;
        cf = nf; cq0 = nq0; cq1 = nq1; cq2 = nq2; cq3 = nq3;
        cc0 = nc0; cc1 = nc1; cc2 = nc2;
      }
    }
  } else {
    // overflow fallback: full face range with per-face row cull
    unsigned yw = (unsigned)__builtin_amdgcn_readfirstlane(y);
    const unsigned* __restrict__ yr = yrange + (size_t)b * F;
    int FPC = (F + NC - 1) / NC;
    int f0 = chunk * FPC;
    int f1 = min(F, f0 + FPC);
    for (int f = f0; f < f1; ++f) {
      unsigned r = yr[f];
      if (yw < (r & 0xffu) || yw > (r >> 8)) continue;
      const FaceRasF fr = fb[f];
      float w0 = fmaf(fr.wx0, pxf, fmaf(fr.wy0, pyf, fr.wc0));
      float w1 = fmaf(fr.wx1, pxf, fmaf(fr.wy1, pyf, fr.wc1));
      float w2 = fmaf(fr.wx2, pxf, fmaf(fr.wy2, pyf, fr.wc2));
      float dmin = fminf(fminf(w0, w1), w2);
      if (dmin > -0.2f) {
        float t = fminf(fmaxf(dmin * 100.0f, -30.0f), 0.0f);
        float pr = __expf(t);
        lsum += __logf(fmaf(-pr, 0.99999990f, 1.0f));
      }
      if (dmin > -fr.epsf) {
        float z = fmaf(w2, fr.z2, fmaf(w1, fr.z1, w0 * fr.z0));
        bool contend = (z < zminf + fr.epsz + weps) & (z > -fr.epsz);
        flag |= (fabsf(dmin) < fr.epsf) & contend;
        flag |= (dmin >= 0.0f) & (fabsf(z) < fr.epsz);
        flag |= (dmin >= 0.0f) & (z > 0.0f) &
                (fabsf(z - zminf) < fr.epsz + weps);
        if ((dmin >= 0.0f) & (z > 0.0f) & (z < zminf)) {
          zminf = z; best = f; weps = fr.epsz;
        }
      }
    }
  }
  int p = b * (HW * HW) + pix;
  size_t idx = (size_t)chunk * P + p;
  pz[idx] = zminf;
  pbv[idx] = (unsigned)best | (flag ? 0x80000000u : 0u);
  pl[idx] = lsum;
  pe[idx] = weps;
}

// exact f64 winner recompute + gather-interpolate + output write (not improb)
__device__ void write_winner(const float* __restrict__ vs_cam,
                             const int* __restrict__ faces,
                             const float* __restrict__ vnorm,
                             const float* __restrict__ attribs,
                             float* __restrict__ out, int P,
                             int b, int V, int F, int pix,
                             int best, bool covered) {
  int p = b * (HW * HW) + pix;
  float imn[3] = {0.f, 0.f, 0.f};
  float ima[3] = {0.f, 0.f, 0.f};
  if (covered) {
    int x = pix & 63, y = pix >> 6;
    const double step = 2.0 / 63.0;
    double px = (x == HW - 1) ? 1.0 : (x * step - 1.0);
    double py = (y == HW - 1) ? 1.0 : (y * step - 1.0);
    int vid[3] = {faces[best * 3 + 0], faces[best * 3 + 1], faces[best * 3 + 2]};
    const float* c0 = vs_cam + (size_t)(b * V + vid[0]) * 3;
    const float* c1 = vs_cam + (size_t)(b * V + vid[1]) * 3;
    const float* c2 = vs_cam + (size_t)(b * V + vid[2]) * 3;
    float v0x = c0[0] / c0[2], v0y = c0[1] / c0[2];
    float v1x = c1[0] / c1[2], v1y = c1[1] / c1[2];
    float v2x = c2[0] / c2[2], v2y = c2[1] / c2[2];
    float dx0 = v2x - v1x, dy0 = v2y - v1y;
    float dx1 = v0x - v2x, dy1 = v0y - v2y;
    float dx2 = v1x - v0x, dy2 = v1y - v0y;
    float A = dx2 * (v2y - v0y) - dy2 * (v2x - v0x);
    if (fabsf(A) < 1e-8f) A = 1e-8f;
    double invA = 1.0 / (double)A;
    double a0 = (double)dx0 * (py - (double)v1y) - (double)dy0 * (px - (double)v1x);
    double a1 = (double)dx1 * (py - (double)v2y) - (double)dy1 * (px - (double)v2x);
    double a2 = (double)dx2 * (py - (double)v0y) - (double)dy2 * (px - (double)v0x);
    double wk[3] = {a0 * invA, a1 * invA, a2 * invA};
    double v[6] = {0, 0, 0, 0, 0, 0};
#pragma unroll
    for (int k = 0; k < 3; ++k) {
      const float* n = vnorm + (size_t)(b * V + vid[k]) * 3;
      float nx = n[0], ny = n[1], nz = n[2];
      float nrm = sqrtf(nx * nx + ny * ny + nz * nz) + 1e-10f;  // f32, like ref
      const float* at = attribs + (((size_t)(b * F + best)) * 3 + k) * 3;
      v[0] += wk[k] * (double)(nx / nrm);
      v[1] += wk[k] * (double)(ny / nrm);
      v[2] += wk[k] * (double)(nz / nrm);
      v[3] += wk[k] * (double)at[0];
      v[4] += wk[k] * (double)at[1];
      v[5] += wk[k] * (double)at[2];
    }
    double nn = sqrt(v[0] * v[0] + v[1] * v[1] + v[2] * v[2]) + 1e-10;
    imn[0] = (float)(v[0] / nn);
    imn[1] = (float)(v[1] / nn);
    imn[2] = (float)(v[2] / nn);
    ima[0] = (float)v[3]; ima[1] = (float)v[4]; ima[2] = (float)v[5];
  }
  float* o_n = out;
  float* o_a = out + (size_t)P * 3;
  float* o_p = out + (size_t)P * 6;
  float* o_i = o_p + P;
  o_n[(size_t)p * 3 + 0] = imn[0];
  o_n[(size_t)p * 3 + 1] = imn[1];
  o_n[(size_t)p * 3 + 2] = imn[2];
  o_a[(size_t)p * 3 + 0] = ima[0];
  o_a[(size_t)p * 3 + 1] = ima[1];
  o_a[(size_t)p * 3 + 2] = ima[2];
  o_i[p] = covered ? (float)best : -1.0f;
}

__global__ void k_final(const float* __restrict__ vs_cam,
                        const int* __restrict__ faces,
                        const float* __restrict__ vnorm,
                        const float* __restrict__ attribs,
                        const float* __restrict__ pz,
                        const unsigned* __restrict__ pbv,
                        const float* __restrict__ pl,
                        const float* __restrict__ pe,
                        float* __restrict__ out,
                        int* __restrict__ cnt, int* __restrict__ list,
                        int B, int V, int F, int NC) {
  int p = blockIdx.x * blockDim.x + threadIdx.x;
  int P = B * HW * HW;
  if (p >= P) return;
  float zmin = INFINITY, weps = 0.f, lsum = 0.f;
  int best = 0;
  bool flag = false;
  for (int c = 0; c < NC; ++c) {
    size_t idx = (size_t)c * P + p;
    float z = pz[idx];
    unsigned pb = pbv[idx];
    float e = pe[idx];
    flag |= (pb >> 31) != 0;
    flag |= fabsf(z - zmin) < (e + weps + 2e-6f);  // cross-chunk near-tie (NaN-safe)
    if (z < zmin) { zmin = z; best = (int)(pb & 0x7fffffffu); weps = e; }
    lsum += pl[idx];
  }
  bool covered = (zmin < 1e38f);
  int b = p >> 12;            // HW*HW = 4096
  int pix = p & 4095;
  write_winner(vs_cam, faces, vnorm, attribs, out, P, b, V, F, pix, best, covered);
  float* o_p = out + (size_t)P * 6;
  o_p[p] = 1.0f - __expf(lsum);
  if (flag) {
    int s = atomicAdd(cnt, 1);
    list[s] = p;
  }
}

// exact f64 re-argmin for flagged pixels: one wave per pixel
__global__ __launch_bounds__(256) void k_repair(
    const float* __restrict__ vs_cam,
    const int* __restrict__ faces,
    const float* __restrict__ vnorm,
    const float* __restrict__ attribs,
    const int* __restrict__ cnt, const int* __restrict__ list,
    float* __restrict__ out, int B, int V, int F) {
  int P = B * HW * HW;
  int gtid = blockIdx.x * blockDim.x + threadIdx.x;
  int wid = gtid >> 6;
  int lane = threadIdx.x & 63;
  int nwaves = (gridDim.x * blockDim.x) >> 6;
  int n = cnt[0];
  for (int i = wid; i < n; i += nwaves) {
    int p = list[i];
    int b = p >> 12;
    int pix = p & 4095;
    int x = pix & 63, y = pix >> 6;
    const double step = 2.0 / 63.0;
    double px = (x == HW - 1) ? 1.0 : (x * step - 1.0);
    double py = (y == HW - 1) ? 1.0 : (y * step - 1.0);
    double zmin = INFINITY;
    int best = 0x7fffffff;
    for (int f = lane; f < F; f += 64) {
      int i0 = faces[f * 3 + 0], i1 = faces[f * 3 + 1], i2 = faces[f * 3 + 2];
      const float* c0 = vs_cam + (size_t)(b * V + i0) * 3;
      const float* c1 = vs_cam + (size_t)(b * V + i1) * 3;
      const float* c2 = vs_cam + (size_t)(b * V + i2) * 3;
      float c0z = c0[2], c1z = c1[2], c2z = c2[2];
      float v0x = c0[0] / c0z, v0y = c0[1] / c0z;
      float v1x = c1[0] / c1z, v1y = c1[1] / c1z;
      float v2x = c2[0] / c2z, v2y = c2[1] / c2z;
      float dx0 = v2x - v1x, dy0 = v2y - v1y;
      float dx1 = v0x - v2x, dy1 = v0y - v2y;
      float dx2 = v1x - v0x, dy2 = v1y - v0y;
      float A = dx2 * (v2y - v0y) - dy2 * (v2x - v0x);
      if (fabsf(A) < 1e-8f) A = 1e-8f;
      double invA = 1.0 / (double)A;
      double a0 = (double)dx0 * (py - (double)v1y) - (double)dy0 * (px - (double)v1x);
      double a1 = (double)dx1 * (py - (double)v2y) - (double)dy1 * (px - (double)v2x);
      double a2 = (double)dx2 * (py - (double)v0y) - (double)dy2 * (px - (double)v0x);
      double w0 = a0 * invA, w1 = a1 * invA, w2 = a2 * invA;
      bool inside = (w0 >= 0.0) & (w1 >= 0.0) & (w2 >= 0.0);
      double z = (w0 * (double)c0z + w1 * (double)c1z) + w2 * (double)c2z;
      if (inside & (z > 0.0) & (z < zmin)) { zmin = z; best = f; }
    }
    // lexicographic (z, idx) wave reduce -> first-occurrence argmin
    for (int off = 32; off; off >>= 1) {
      double zo = __shfl_down(zmin, off);
      int bo = __shfl_down(best, off);
      if ((zo < zmin) || ((zo == zmin) && (bo < best))) { zmin = zo; best = bo; }
    }
    if (lane == 0) {
      bool covered = (zmin < 1e300);
      write_winner(vs_cam, faces, vnorm, attribs, out, P, b, V, F, pix, best, covered);
    }
  }
}

extern "C" void kernel_launch(void* const* d_in, const int* in_sizes, int n_in,
                              void* d_out, int out_size, void* d_ws, size_t ws_size,
                              hipStream_t stream) {
  const float* vert    = (const float*)d_in[0];
  const int*   faces   = (const int*)d_in[1];
  const float* attribs = (const float*)d_in[2];
  const float* rot     = (const float*)d_in[3];
  const float* trans   = (const float*)d_in[4];
  int B = in_sizes[4] / 3;
  int V = in_sizes[0] / (3 * B);
  int F = in_sizes[1] / 3;
  int P = B * HW * HW;

  size_t szFras  = sizeof(FaceRasF) * (size_t)B * F;
  size_t szYr    = 4ull * (size_t)B * F;
  size_t szVs    = 12ull * (size_t)B * V;
  size_t szVn    = 12ull * (size_t)B * V;
  size_t szRowC  = 4ull * 256 * CSTR;          // rowcnt (strided)
  size_t szRowF  = 4ull * 256 * CSTR;          // rowfill (strided)
  size_t szRowS  = 4ull * 257;                 // rowstart
  size_t szCnt   = 4;
  size_t szPlist = 4ull * (size_t)P;
  size_t fixed   = szFras + szYr + szVs + szVn + szRowC + szRowF + szRowS +
                   szCnt + szPlist + 1024;

  // pick chunk count NC and face-list capacity lcap from available workspace.
  // with exact y-ranges actual usage is ~350K entries; prefer lcap >= 600K.
  size_t maxcap = (size_t)B * F * 64ull;       // exact worst case: never overflows
  int NC = 32;
  size_t lcap = 0;
  for (;;) {
    size_t need = fixed + (size_t)P * 16ull * (size_t)NC;
    lcap = (ws_size > need) ? (ws_size - need) / 4 : 0;
    if (lcap > maxcap) lcap = maxcap;
    if (NC == 8) break;
    if (lcap >= maxcap || lcap >= 600000) break;
    NC >>= 1;
  }

  char* w = (char*)d_ws;
  FaceRasF* frasF  = (FaceRasF*)w; w += szFras;            // 64B-aligned
  float* pz        = (float*)w;    w += 4ull * P * NC;
  unsigned* pbv    = (unsigned*)w; w += 4ull * P * NC;
  float* pl        = (float*)w;    w += 4ull * P * NC;
  float* pe        = (float*)w;    w += 4ull * P * NC;
  unsigned* yrange = (unsigned*)w; w += szYr;
  float* vs_cam    = (float*)w;    w += szVs;
  float* vnorm     = (float*)w;    w += szVn;
  unsigned* rowcnt  = (unsigned*)w; w += szRowC;           // contiguous zero region:
  unsigned* rowfill = (unsigned*)w; w += szRowF;           //   rowcnt+rowfill+cnt
  int* cnt         = (int*)w;      w += szCnt;
  unsigned* rowstart= (unsigned*)w; w += szRowS;
  int* list        = (int*)w;      w += szPlist;
  w = (char*)(((size_t)w + 3) & ~(size_t)3);
  unsigned* flist  = (unsigned*)w; /* lcap entries */

  // single memset: rowcnt + rowfill + cnt are laid out contiguously
  hipMemsetAsync(rowcnt, 0, szRowC + szRowF + szCnt, stream);
  k_transform<<<(B * V + 255) / 256, 256, 0, stream>>>(vert, rot, trans, vs_cam,
                                                       vnorm, B, V);
  dim3 fg((unsigned)((F + 255) / 256), (unsigned)B);
  k_facepre<<<fg, 256, 0, stream>>>(vs_cam, faces, frasF, yrange, vnorm, rowcnt,
                                    B, V, F);
  k_scan<<<1, 256, 0, stream>>>(rowcnt, rowstart);
  k_emit<<<fg, 256, 0, stream>>>(yrange, rowstart, rowfill, flist, (unsigned)lcap, F);
  dim3 rg((unsigned)(B * PPB), (unsigned)NC);
  k_raster<<<rg, 256, 0, stream>>>(frasF, yrange, rowstart, flist, pz, pbv, pl, pe,
                                   (unsigned)lcap, F, NC, P);
  k_final<<<(P + 255) / 256, 256, 0, stream>>>(vs_cam, faces, vnorm, attribs,
                                               pz, pbv, pl, pe,
                                               (float*)d_out, cnt, list, B, V, F, NC);
  k_repair<<<256, 256, 0, stream>>>(vs_cam, faces, vnorm, attribs, cnt, list,
                                    (float*)d_out, B, V, F);
}

// Round 4
// 262.013 us; speedup vs baseline: 1.3252x; 1.3252x over previous
//
#include <hip/hip_runtime.h>
#include <math.h>

#define HW 64
#define PPB 16   // 256-thread blocks per 64x64 image (wave = one row)
#define CSTR 8   // row-counter stride (words) to spread atomics across L2 channels

// f32 fast-raster record: 16 floats = 64 B
// float4 view: q0=(wx0,wy0,wc0,wx1) q1=(wy1,wc1,wx2,wy2) q2=(wc2,z0,z1,z2) q3=(epsf,epsz,pad,pad)
struct FaceRasF {
  float wx0, wy0, wc0;
  float wx1, wy1, wc1;
  float wx2, wy2, wc2;
  float z0, z1, z2;
  float epsf, epsz;
  float pad0, pad1;
};

__global__ void k_transform(const float* __restrict__ vert,
                            const float* __restrict__ rot,
                            const float* __restrict__ trans,
                            float* __restrict__ vs_cam,
                            float* __restrict__ vnorm, int B, int V) {
  int i = blockIdx.x * blockDim.x + threadIdx.x;
  if (i >= B * V) return;
  int b = i / V;
  float x = vert[i * 3 + 0], y = vert[i * 3 + 1], z = vert[i * 3 + 2];
  const float* R = rot + b * 9;
  const float* t = trans + b * 3;
  vs_cam[i * 3 + 0] = ((x * R[0] + y * R[1]) + z * R[2]) + t[0];
  vs_cam[i * 3 + 1] = ((x * R[3] + y * R[4]) + z * R[5]) + t[1];
  vs_cam[i * 3 + 2] = ((x * R[6] + y * R[7]) + z * R[8]) + t[2];
  vnorm[i * 3 + 0] = 0.f;   // zero-init here: saves a 192KB memset launch
  vnorm[i * 3 + 1] = 0.f;
  vnorm[i * 3 + 2] = 0.f;
}

// face precompute + DIRECT bucket emit (count/scan/emit fused: row buckets of
// capacity CAP replace the CSR lists -> two fewer kernel launches).
// grid: ((F+255)/256, B) so each wave has uniform b (ballot aggregation).
__global__ void k_facepre(const float* __restrict__ vs_cam,
                          const int* __restrict__ faces,
                          FaceRasF* __restrict__ frasF,
                          unsigned* __restrict__ yrange,
                          float* __restrict__ vnorm,
                          unsigned* __restrict__ rowcnt,
                          unsigned* __restrict__ rowbuk,
                          unsigned CAP, int B, int V, int F) {
  int f = blockIdx.x * blockDim.x + threadIdx.x;
  int b = blockIdx.y;
  bool valid = (f < F);
  int r0 = 1, r1 = 0;
  if (valid) {
    int i = b * F + f;
    int i0 = faces[f * 3 + 0], i1 = faces[f * 3 + 1], i2 = faces[f * 3 + 2];
    const float* c0 = vs_cam + (size_t)(b * V + i0) * 3;
    const float* c1 = vs_cam + (size_t)(b * V + i1) * 3;
    const float* c2 = vs_cam + (size_t)(b * V + i2) * 3;
    float c0x = c0[0], c0y = c0[1], c0z = c0[2];
    float c1x = c1[0], c1y = c1[1], c1z = c1[2];
    float c2x = c2[0], c2y = c2[1], c2z = c2[2];
    float v0x = c0x / c0z, v0y = c0y / c0z;
    float v1x = c1x / c1z, v1y = c1y / c1z;
    float v2x = c2x / c2z, v2y = c2y / c2z;
    float dx0 = v2x - v1x, dy0 = v2y - v1y;   // edge(v1,v2), anchor v1
    float dx1 = v0x - v2x, dy1 = v0y - v2y;   // edge(v2,v0), anchor v2
    float dx2 = v1x - v0x, dy2 = v1y - v0y;   // edge(v0,v1), anchor v0
    float Araw = dx2 * (v2y - v0y) - dy2 * (v2x - v0x);
    float A = (fabsf(Araw) < 1e-8f) ? 1e-8f : Araw;
    double invA = 1.0 / (double)A;
    double wx0 = -(double)dy0 * invA, wy0 = (double)dx0 * invA;
    double wc0 = ((double)dy0 * (double)v1x - (double)dx0 * (double)v1y) * invA;
    double wx1 = -(double)dy1 * invA, wy1 = (double)dx1 * invA;
    double wc1 = ((double)dy1 * (double)v2x - (double)dx1 * (double)v2y) * invA;
    double wx2 = -(double)dy2 * invA, wy2 = (double)dx2 * invA;
    double wc2 = ((double)dy2 * (double)v0x - (double)dx2 * (double)v0y) * invA;
    double m0 = fabs(wx0) + fabs(wy0) + fabs(wc0);
    double m1 = fabs(wx1) + fabs(wy1) + fabs(wc1);
    double m2 = fabs(wx2) + fabs(wy2) + fabs(wc2);
    double mm = fmax(fmax(m0, m1), m2);
    float epsf = fmaxf((float)(6e-7 * mm), 3e-7f);
    float zs = fabsf(c0z) + fabsf(c1z) + fabsf(c2z);
    float epsz = (epsf + 4e-6f) * zs;
    FaceRasF fr;
    fr.wx0 = (float)wx0; fr.wy0 = (float)wy0; fr.wc0 = (float)wc0;
    fr.wx1 = (float)wx1; fr.wy1 = (float)wy1; fr.wc1 = (float)wc1;
    fr.wx2 = (float)wx2; fr.wy2 = (float)wy2; fr.wc2 = (float)wc2;
    fr.z0 = c0z; fr.z1 = c1z; fr.z2 = c2z;
    fr.epsf = epsf; fr.epsz = epsz; fr.pad0 = 0.f; fr.pad1 = 0.f;
    frasF[i] = fr;
    // EXACT y-range of {dmin >= -band} via the barycentric slab:
    // w0+w1+w2 == 1, so dmin>=-b <=> all w_i>=-b, and y = sum w_i*v_iy over that
    // slab has exact extremes vext + b*(3*vext - sum).
    float band = fmaxf(0.202f, 1.6f * epsf);
    if (fabsf(Araw) < 1e-8f) {
      r0 = 0; r1 = 63;            // degenerate clamp: sum(w) != 1, no bound
    } else {
      float vmin = fminf(v0y, fminf(v1y, v2y));
      float vmax = fmaxf(v0y, fmaxf(v1y, v2y));
      float s3 = v0y + v1y + v2y;
      float b1 = band * 1.05f + 1e-4f;        // slack for f32 rounding
      float ylo = vmin + b1 * (3.f * vmin - s3);
      float yhi = vmax + b1 * (3.f * vmax - s3);
      if (yhi < -1.001f || ylo > 1.001f) { r0 = 1; r1 = 0; }
      else {
        r0 = max(0, (int)floorf((ylo + 1.0f) * 31.5f) - 1);
        r1 = min(63, (int)ceilf((yhi + 1.0f) * 31.5f) + 1);
        if (r0 > r1) { r0 = 1; r1 = 0; }
      }
    }
    yrange[i] = (unsigned)r0 | ((unsigned)r1 << 8);
    // face normal -> vertex normal scatter (f32 atomics)
    float e1x = c1x - c0x, e1y = c1y - c0y, e1z = c1z - c0z;
    float e2x = c2x - c0x, e2y = c2y - c0y, e2z = c2z - c0z;
    float nx = e1y * e2z - e1z * e2y;
    float ny = e1z * e2x - e1x * e2z;
    float nz = e1x * e2y - e1y * e2x;
    float* vn0 = vnorm + (size_t)(b * V + i0) * 3;
    float* vn1 = vnorm + (size_t)(b * V + i1) * 3;
    float* vn2 = vnorm + (size_t)(b * V + i2) * 3;
    atomicAdd(vn0 + 0, nx); atomicAdd(vn0 + 1, ny); atomicAdd(vn0 + 2, nz);
    atomicAdd(vn1 + 0, nx); atomicAdd(vn1 + 1, ny); atomicAdd(vn1 + 2, nz);
    atomicAdd(vn2 + 0, nx); atomicAdd(vn2 + 1, ny); atomicAdd(vn2 + 2, nz);
  }
  // wave-aggregated bucket append, trimmed to the wave's row union
  int lane = threadIdx.x & 63;
  bool has = valid && r0 <= r1;
  int rmin = has ? r0 : 64, rmax = has ? r1 : -1;
  for (int off = 32; off; off >>= 1) {
    rmin = min(rmin, __shfl_xor(rmin, off));
    rmax = max(rmax, __shfl_xor(rmax, off));
  }
  for (int r = rmin; r <= rmax; ++r) {
    bool in = has && r >= r0 && r <= r1;
    unsigned long long m = __ballot(in);
    if (m == 0ull) continue;
    int row = (b << 6) | r;
    int leader = __ffsll(m) - 1;
    unsigned base = 0;
    if (lane == leader) base = atomicAdd(&rowcnt[row * CSTR], (unsigned)__popcll(m));
    base = (unsigned)__shfl((int)base, leader);
    if (in) {
      unsigned pos = base + (unsigned)__popcll(m & ((1ull << lane) - 1ull));
      if (pos < CAP) rowbuk[(size_t)row * CAP + pos] = (unsigned)f;
    }
  }
}

// f32 screened raster: LDS-staged batches, broadcast ds_read walk.
// (R2 serial s_load chain ~1500cy/entry; R3 shuffle chain ~2300cy/entry — both
// latency-bound. Staging loads 64 records in ONE memory latency, then the walk
// is issue-bound broadcast LDS reads with affine addresses.)
__global__ __launch_bounds__(256) void k_raster(
    const FaceRasF* __restrict__ frasF,
    const unsigned* __restrict__ yrange,
    const unsigned* __restrict__ rowcnt,
    const unsigned* __restrict__ rowbuk,
    float4* __restrict__ pc,
    unsigned CAP, int F, int NC, int P) {
  __shared__ float4 lds[4][2][64 * 3];   // [wave][buf][entry*3] = 24 KB
  int b = blockIdx.x / PPB;
  int pix = (blockIdx.x % PPB) * 256 + threadIdx.x;
  int chunk = blockIdx.y;
  int y = pix >> 6, x = pix & 63;
  int wv = threadIdx.x >> 6;
  int lane = threadIdx.x & 63;
  const double step = 2.0 / 63.0;
  double pxd = (x == HW - 1) ? 1.0 : (x * step - 1.0);
  double pyd = (y == HW - 1) ? 1.0 : (y * step - 1.0);
  float pxf = (float)pxd, pyf = (float)pyd;
  const float4* __restrict__ fb4 = (const float4*)(frasF + (size_t)b * F);
  float zminf = INFINITY;
  float weps = 0.f;
  int best = 0;
  bool flag = false;
  float lsum = 0.f;

  int row = (b << 6) | y;                      // wave-uniform: wave = one row
  unsigned fill = rowcnt[row * CSTR];
  if (fill <= CAP) {
    // dense bucket path: entries for this row are complete in rowbuk[row*CAP ..]
    const unsigned* __restrict__ rl = rowbuk + (size_t)row * CAP;
    unsigned per = (fill + (unsigned)NC - 1) / (unsigned)NC;
    unsigned i0 = min(fill, (unsigned)chunk * per);
    unsigned i1 = min(fill, i0 + per);
    // stage batch at [base, base+64) into lds[wv][buf]; pre-fold ce = wy*py+wc
    auto STAGE = [&](int buf, unsigned base) {
      unsigned j = base + (unsigned)lane;
      if (j < i1) {
        int fidx = (int)rl[j];
        size_t o = (size_t)fidx * 4;
        float4 q0 = fb4[o + 0], q1 = fb4[o + 1], q2 = fb4[o + 2], q3 = fb4[o + 3];
        float ce0 = fmaf(q0.y, pyf, q0.z);
        float ce1 = fmaf(q1.x, pyf, q1.y);
        float ce2 = fmaf(q1.w, pyf, q2.x);
        float4* d = &lds[wv][buf][lane * 3];
        d[0] = make_float4(q0.x, q0.w, q1.z, ce0);           // wx0,wx1,wx2,ce0
        d[1] = make_float4(ce1, ce2, q2.y, q2.z);            // ce1,ce2,z0,z1
        d[2] = make_float4(q2.w, q3.x, q3.y, __int_as_float(fidx)); // z2,ef,ez,f
      }
    };
    if (i0 < i1) {
      STAGE(0, i0);
      int buf = 0;
      for (unsigned base = i0; base < i1; base += 64, buf ^= 1) {
        if (base + 64 < i1) STAGE(buf ^ 1, base + 64);  // prefetch next batch
        int n = (int)min(64u, i1 - base);
        const float4* __restrict__ L = lds[wv][buf];
#pragma unroll 4
        for (int k = 0; k < n; ++k) {
          float4 r0 = L[k * 3 + 0];
          float4 r1 = L[k * 3 + 1];
          float4 r2 = L[k * 3 + 2];
          float w0 = fmaf(r0.x, pxf, r0.w);   // == fmaf(wx,px,fmaf(wy,py,wc))
          float w1 = fmaf(r0.y, pxf, r1.x);   //    bit-identical to reference order
          float w2 = fmaf(r0.z, pxf, r1.y);
          float dmin = fminf(fminf(w0, w1), w2);
          if (dmin > -0.2f) {
            // clip(dmin/sigma,-30,0): dmin<=-0.2 contributes <=2e-9, skipped
            float t = fminf(fmaxf(dmin * 100.0f, -30.0f), 0.0f);
            float pr = __expf(t);             // inside -> t=0 -> pr=1 exactly
            lsum += __logf(fmaf(-pr, 0.99999990f, 1.0f));
          }
          float ef = r2.y;
          if (dmin > -ef) {
            float z = fmaf(w2, r2.x, fmaf(w1, r1.w, w0 * r1.z));
            float ez = r2.z;
            bool contend = (z < zminf + ez + weps) & (z > -ez);
            flag |= (fabsf(dmin) < ef) & contend;            // inside-sign ambiguous
            flag |= (dmin >= 0.0f) & (fabsf(z) < ez);        // z>0 boundary ambiguous
            flag |= (dmin >= 0.0f) & (z > 0.0f) &
                    (fabsf(z - zminf) < ez + weps);          // z-order ambiguous
            if ((dmin >= 0.0f) & (z > 0.0f) & (z < zminf)) { // ties repaired in f64
              zminf = z; best = __float_as_int(r2.w); weps = ez;
            }
          }
        }
      }
    }
  } else {
    // overflow fallback: full face range with per-face row cull
    unsigned yw = (unsigned)__builtin_amdgcn_readfirstlane(y);
    const unsigned* __restrict__ yr = yrange + (size_t)b * F;
    const FaceRasF* __restrict__ fb = frasF + (size_t)b * F;
    int FPC = (F + NC - 1) / NC;
    int f0 = chunk * FPC;
    int f1 = min(F, f0 + FPC);
    for (int f = f0; f < f1; ++f) {
      unsigned r = yr[f];
      if (yw < (r & 0xffu) || yw > (r >> 8)) continue;
      const FaceRasF fr = fb[f];
      float w0 = fmaf(fr.wx0, pxf, fmaf(fr.wy0, pyf, fr.wc0));
      float w1 = fmaf(fr.wx1, pxf, fmaf(fr.wy1, pyf, fr.wc1));
      float w2 = fmaf(fr.wx2, pxf, fmaf(fr.wy2, pyf, fr.wc2));
      float dmin = fminf(fminf(w0, w1), w2);
      if (dmin > -0.2f) {
        float t = fminf(fmaxf(dmin * 100.0f, -30.0f), 0.0f);
        float pr = __expf(t);
        lsum += __logf(fmaf(-pr, 0.99999990f, 1.0f));
      }
      if (dmin > -fr.epsf) {
        float z = fmaf(w2, fr.z2, fmaf(w1, fr.z1, w0 * fr.z0));
        bool contend = (z < zminf + fr.epsz + weps) & (z > -fr.epsz);
        flag |= (fabsf(dmin) < fr.epsf) & contend;
        flag |= (dmin >= 0.0f) & (fabsf(z) < fr.epsz);
        flag |= (dmin >= 0.0f) & (z > 0.0f) &
                (fabsf(z - zminf) < fr.epsz + weps);
        if ((dmin >= 0.0f) & (z > 0.0f) & (z < zminf)) {
          zminf = z; best = f; weps = fr.epsz;
        }
      }
    }
  }
  int p = b * (HW * HW) + pix;
  unsigned pbv = (unsigned)best | (flag ? 0x80000000u : 0u);
  pc[(size_t)chunk * P + p] = make_float4(zminf, lsum, weps, __uint_as_float(pbv));
}

// exact f64 winner recompute + gather-interpolate + output write (not improb)
__device__ void write_winner(const float* __restrict__ vs_cam,
                             const int* __restrict__ faces,
                             const float* __restrict__ vnorm,
                             const float* __restrict__ attribs,
                             float* __restrict__ out, int P,
                             int b, int V, int F, int pix,
                             int best, bool covered) {
  int p = b * (HW * HW) + pix;
  float imn[3] = {0.f, 0.f, 0.f};
  float ima[3] = {0.f, 0.f, 0.f};
  if (covered) {
    int x = pix & 63, y = pix >> 6;
    const double step = 2.0 / 63.0;
    double px = (x == HW - 1) ? 1.0 : (x * step - 1.0);
    double py = (y == HW - 1) ? 1.0 : (y * step - 1.0);
    int vid[3] = {faces[best * 3 + 0], faces[best * 3 + 1], faces[best * 3 + 2]};
    const float* c0 = vs_cam + (size_t)(b * V + vid[0]) * 3;
    const float* c1 = vs_cam + (size_t)(b * V + vid[1]) * 3;
    const float* c2 = vs_cam + (size_t)(b * V + vid[2]) * 3;
    float v0x = c0[0] / c0[2], v0y = c0[1] / c0[2];
    float v1x = c1[0] / c1[2], v1y = c1[1] / c1[2];
    float v2x = c2[0] / c2[2], v2y = c2[1] / c2[2];
    float dx0 = v2x - v1x, dy0 = v2y - v1y;
    float dx1 = v0x - v2x, dy1 = v0y - v2y;
    float dx2 = v1x - v0x, dy2 = v1y - v0y;
    float A = dx2 * (v2y - v0y) - dy2 * (v2x - v0x);
    if (fabsf(A) < 1e-8f) A = 1e-8f;
    double invA = 1.0 / (double)A;
    double a0 = (double)dx0 * (py - (double)v1y) - (double)dy0 * (px - (double)v1x);
    double a1 = (double)dx1 * (py - (double)v2y) - (double)dy1 * (px - (double)v2x);
    double a2 = (double)dx2 * (py - (double)v0y) - (double)dy2 * (px - (double)v0x);
    double wk[3] = {a0 * invA, a1 * invA, a2 * invA};
    double v[6] = {0, 0, 0, 0, 0, 0};
#pragma unroll
    for (int k = 0; k < 3; ++k) {
      const float* n = vnorm + (size_t)(b * V + vid[k]) * 3;
      float nx = n[0], ny = n[1], nz = n[2];
      float nrm = sqrtf(nx * nx + ny * ny + nz * nz) + 1e-10f;  // f32, like ref
      const float* at = attribs + (((size_t)(b * F + best)) * 3 + k) * 3;
      v[0] += wk[k] * (double)(nx / nrm);
      v[1] += wk[k] * (double)(ny / nrm);
      v[2] += wk[k] * (double)(nz / nrm);
      v[3] += wk[k] * (double)at[0];
      v[4] += wk[k] * (double)at[1];
      v[5] += wk[k] * (double)at[2];
    }
    double nn = sqrt(v[0] * v[0] + v[1] * v[1] + v[2] * v[2]) + 1e-10;
    imn[0] = (float)(v[0] / nn);
    imn[1] = (float)(v[1] / nn);
    imn[2] = (float)(v[2] / nn);
    ima[0] = (float)v[3]; ima[1] = (float)v[4]; ima[2] = (float)v[5];
  }
  float* o_n = out;
  float* o_a = out + (size_t)P * 3;
  float* o_p = out + (size_t)P * 6;
  float* o_i = o_p + P;
  o_n[(size_t)p * 3 + 0] = imn[0];
  o_n[(size_t)p * 3 + 1] = imn[1];
  o_n[(size_t)p * 3 + 2] = imn[2];
  o_a[(size_t)p * 3 + 0] = ima[0];
  o_a[(size_t)p * 3 + 1] = ima[1];
  o_a[(size_t)p * 3 + 2] = ima[2];
  o_i[p] = covered ? (float)best : -1.0f;
}

__global__ void k_final(const float* __restrict__ vs_cam,
                        const int* __restrict__ faces,
                        const float* __restrict__ vnorm,
                        const float* __restrict__ attribs,
                        const float4* __restrict__ pc,
                        float* __restrict__ out,
                        int* __restrict__ cnt, int* __restrict__ list,
                        int B, int V, int F, int NC) {
  int p = blockIdx.x * blockDim.x + threadIdx.x;
  int P = B * HW * HW;
  if (p >= P) return;
  float zmin = INFINITY, weps = 0.f, lsum = 0.f;
  int best = 0;
  bool flag = false;
  for (int c = 0; c < NC; ++c) {
    float4 q = pc[(size_t)c * P + p];
    float z = q.x;
    float e = q.z;
    unsigned pb = __float_as_uint(q.w);
    flag |= (pb >> 31) != 0;
    flag |= fabsf(z - zmin) < (e + weps + 2e-6f);  // cross-chunk near-tie (NaN-safe)
    if (z < zmin) { zmin = z; best = (int)(pb & 0x7fffffffu); weps = e; }
    lsum += q.y;
  }
  bool covered = (zmin < 1e38f);
  int b = p >> 12;            // HW*HW = 4096
  int pix = p & 4095;
  write_winner(vs_cam, faces, vnorm, attribs, out, P, b, V, F, pix, best, covered);
  float* o_p = out + (size_t)P * 6;
  o_p[p] = 1.0f - __expf(lsum);
  if (flag) {
    int s = atomicAdd(cnt, 1);
    list[s] = p;
  }
}

// exact f64 re-argmin for flagged pixels: one wave per pixel
__global__ __launch_bounds__(256) void k_repair(
    const float* __restrict__ vs_cam,
    const int* __restrict__ faces,
    const float* __restrict__ vnorm,
    const float* __restrict__ attribs,
    const int* __restrict__ cnt, const int* __restrict__ list,
    float* __restrict__ out, int B, int V, int F) {
  int P = B * HW * HW;
  int gtid = blockIdx.x * blockDim.x + threadIdx.x;
  int wid = gtid >> 6;
  int lane = threadIdx.x & 63;
  int nwaves = (gridDim.x * blockDim.x) >> 6;
  int n = cnt[0];
  for (int i = wid; i < n; i += nwaves) {
    int p = list[i];
    int b = p >> 12;
    int pix = p & 4095;
    int x = pix & 63, y = pix >> 6;
    const double step = 2.0 / 63.0;
    double px = (x == HW - 1) ? 1.0 : (x * step - 1.0);
    double py = (y == HW - 1) ? 1.0 : (y * step - 1.0);
    double zmin = INFINITY;
    int best = 0x7fffffff;
    for (int f = lane; f < F; f += 64) {
      int i0 = faces[f * 3 + 0], i1 = faces[f * 3 + 1], i2 = faces[f * 3 + 2];
      const float* c0 = vs_cam + (size_t)(b * V + i0) * 3;
      const float* c1 = vs_cam + (size_t)(b * V + i1) * 3;
      const float* c2 = vs_cam + (size_t)(b * V + i2) * 3;
      float c0z = c0[2], c1z = c1[2], c2z = c2[2];
      float v0x = c0[0] / c0z, v0y = c0[1] / c0z;
      float v1x = c1[0] / c1z, v1y = c1[1] / c1z;
      float v2x = c2[0] / c2z, v2y = c2[1] / c2z;
      float dx0 = v2x - v1x, dy0 = v2y - v1y;
      float dx1 = v0x - v2x, dy1 = v0y - v2y;
      float dx2 = v1x - v0x, dy2 = v1y - v0y;
      float A = dx2 * (v2y - v0y) - dy2 * (v2x - v0x);
      if (fabsf(A) < 1e-8f) A = 1e-8f;
      double invA = 1.0 / (double)A;
      double a0 = (double)dx0 * (py - (double)v1y) - (double)dy0 * (px - (double)v1x);
      double a1 = (double)dx1 * (py - (double)v2y) - (double)dy1 * (px - (double)v2x);
      double a2 = (double)dx2 * (py - (double)v0y) - (double)dy2 * (px - (double)v0x);
      double w0 = a0 * invA, w1 = a1 * invA, w2 = a2 * invA;
      bool inside = (w0 >= 0.0) & (w1 >= 0.0) & (w2 >= 0.0);
      double z = (w0 * (double)c0z + w1 * (double)c1z) + w2 * (double)c2z;
      if (inside & (z > 0.0) & (z < zmin)) { zmin = z; best = f; }
    }
    // lexicographic (z, idx) wave reduce -> first-occurrence argmin
    for (int off = 32; off; off >>= 1) {
      double zo = __shfl_down(zmin, off);
      int bo = __shfl_down(best, off);
      if ((zo < zmin) || ((zo == zmin) && (bo < best))) { zmin = zo; best = bo; }
    }
    if (lane == 0) {
      bool covered = (zmin < 1e300);
      write_winner(vs_cam, faces, vnorm, attribs, out, P, b, V, F, pix, best, covered);
    }
  }
}

extern "C" void kernel_launch(void* const* d_in, const int* in_sizes, int n_in,
                              void* d_out, int out_size, void* d_ws, size_t ws_size,
                              hipStream_t stream) {
  const float* vert    = (const float*)d_in[0];
  const int*   faces   = (const int*)d_in[1];
  const float* attribs = (const float*)d_in[2];
  const float* rot     = (const float*)d_in[3];
  const float* trans   = (const float*)d_in[4];
  int B = in_sizes[4] / 3;
  int V = in_sizes[0] / (3 * B);
  int F = in_sizes[1] / 3;
  int P = B * HW * HW;
  int NR = B * HW;                              // total (b,row) buckets

  size_t szFras  = sizeof(FaceRasF) * (size_t)B * F;
  size_t szYr    = 4ull * (size_t)B * F;
  size_t szVs    = 12ull * (size_t)B * V;
  size_t szVn    = 12ull * (size_t)B * V;
  size_t szRowC  = 4ull * (size_t)NR * CSTR;    // rowcnt (strided)
  size_t szCnt   = 4;
  size_t szPlist = 4ull * (size_t)P;
  size_t fixed   = szFras + szYr + szVs + szVn + szRowC + szCnt + szPlist + 1024;

  // pick chunk count NC and per-row bucket capacity CAP from workspace.
  // CAP = F is the exact worst case (a face appears at most once per row).
  int NC = 16;
  size_t CAP = (size_t)F;
  while (NC > 4 && fixed + (size_t)P * 16ull * NC + 4ull * NR * CAP > ws_size)
    NC >>= 1;
  while (CAP > 1024 && fixed + (size_t)P * 16ull * NC + 4ull * NR * CAP > ws_size)
    CAP >>= 1;                                  // may overflow -> raster fallback

  char* w = (char*)d_ws;
  FaceRasF* frasF  = (FaceRasF*)w; w += szFras;            // 64B-aligned
  float4* pc       = (float4*)w;   w += (size_t)P * 16ull * NC;
  unsigned* rowbuk = (unsigned*)w; w += 4ull * NR * CAP;
  unsigned* yrange = (unsigned*)w; w += szYr;
  float* vs_cam    = (float*)w;    w += szVs;
  float* vnorm     = (float*)w;    w += szVn;
  unsigned* rowcnt = (unsigned*)w; w += szRowC;            // contiguous zero region:
  int* cnt         = (int*)w;      w += szCnt;             //   rowcnt + cnt
  int* list        = (int*)w;      /* P entries */

  // single memset: rowcnt + cnt are laid out contiguously
  hipMemsetAsync(rowcnt, 0, szRowC + szCnt, stream);
  k_transform<<<(B * V + 255) / 256, 256, 0, stream>>>(vert, rot, trans, vs_cam,
                                                       vnorm, B, V);
  dim3 fg((unsigned)((F + 255) / 256), (unsigned)B);
  k_facepre<<<fg, 256, 0, stream>>>(vs_cam, faces, frasF, yrange, vnorm, rowcnt,
                                    rowbuk, (unsigned)CAP, B, V, F);
  dim3 rg((unsigned)(B * PPB), (unsigned)NC);
  k_raster<<<rg, 256, 0, stream>>>(frasF, yrange, rowcnt, rowbuk, pc,
                                   (unsigned)CAP, F, NC, P);
  k_final<<<(P + 255) / 256, 256, 0, stream>>>(vs_cam, faces, vnorm, attribs,
                                               pc, (float*)d_out, cnt, list,
                                               B, V, F, NC);
  k_repair<<<256, 256, 0, stream>>>(vs_cam, faces, vnorm, attribs, cnt, list,
                                    (float*)d_out, B, V, F);
}